// Round 2
// baseline (142.249 us; speedup 1.0000x reference)
//
#include <hip/hip_runtime.h>
#include <math.h>

// NUFFT type-2 exact NUDFT: out[b,c,k] = sum_{x,y} img[b,c,x,y] * exp(-i*(om_x*(x-64) + om_y*(y-64)))
// R2: lane<->k mapping, phase via complex geometric recurrence. 8 waves/block (16 waves/CU),
// dual y-phase chains (even/odd) for 2x ILP, float4 uniform image loads.

constexpr int Bn = 2, Cn = 8, Kn = 2048, Hn = 128, Wn = 128;
constexpr int KPB = 64;          // k's per block (one wave-width)
constexpr int WAVES = 8;         // waves per block, each takes an x-slab
constexpr int XPW = Hn / WAVES;  // 16 rows per wave

template<int OUT_COMPLEX>
__global__ __launch_bounds__(512, 2)
void nufft_kernel(const float* __restrict__ img_re,
                  const float* __restrict__ img_im,
                  const float* __restrict__ traj,
                  float* __restrict__ out)
{
    const int blocks_per_bc = Kn / KPB;           // 32
    const int bc   = blockIdx.x / blocks_per_bc;  // 0..15 (b*C+c)
    const int kc   = blockIdx.x % blocks_per_bc;
    const int wave = threadIdx.x >> 6;
    const int lane = threadIdx.x & 63;
    const int k    = kc * KPB + lane;

    // kspace_traj layout: (B, C, 2, K)
    const float om_x = traj[(size_t)(bc * 2 + 0) * Kn + k];
    const float om_y = traj[(size_t)(bc * 2 + 1) * Kn + k];

    float s, c;
    sincosf(om_x, &s, &c);
    const float stepx_re = c, stepx_im = -s;      // exp(-i*om_x)
    sincosf(om_y, &s, &c);
    const float stepy_re = c, stepy_im = -s;      // exp(-i*om_y)
    // stepy^2 for the dual even/odd chains
    const float sy2_re = fmaf(stepy_re, stepy_re, -stepy_im * stepy_im);
    const float sy2_im = 2.f * stepy_re * stepy_im;

    const int x0 = wave * XPW;
    sincosf(-om_x * (float)(x0 - Hn / 2), &s, &c);
    float rowp_re = c, rowp_im = s;               // exp(-i*om_x*(x0-64))
    sincosf(om_y * (float)(Wn / 2), &s, &c);
    const float y0_re = c, y0_im = s;             // exp(+i*64*om_y) = phase at y=0
    // phase at y=1: y0 * stepy
    const float y1_re = fmaf(y0_re, stepy_re, -y0_im * stepy_im);
    const float y1_im = fmaf(y0_re, stepy_im,  y0_im * stepy_re);

    float a0r = 0.f, a0i = 0.f, a1r = 0.f, a1i = 0.f;

    const float4* pre = (const float4*)(img_re + (size_t)bc * Hn * Wn + (size_t)x0 * Wn);
    const float4* pim = (const float4*)(img_im + (size_t)bc * Hn * Wn + (size_t)x0 * Wn);

    for (int xr = 0; xr < XPW; ++xr) {
        // chains at (x, y=0) and (x, y=1)
        float c0r = rowp_re * y0_re - rowp_im * y0_im;
        float c0i = rowp_re * y0_im + rowp_im * y0_re;
        float c1r = rowp_re * y1_re - rowp_im * y1_im;
        float c1i = rowp_re * y1_im + rowp_im * y1_re;
        #pragma unroll 8
        for (int yq = 0; yq < Wn / 4; ++yq) {
            const float4 vr = pre[yq];   // wave-uniform 16B loads
            const float4 vi = pim[yq];
            // elements 4*yq+0 (chain0), 4*yq+1 (chain1)
            a0r = fmaf(vr.x, c0r, a0r); a0r = fmaf(-vi.x, c0i, a0r);
            a0i = fmaf(vr.x, c0i, a0i); a0i = fmaf( vi.x, c0r, a0i);
            a1r = fmaf(vr.y, c1r, a1r); a1r = fmaf(-vi.y, c1i, a1r);
            a1i = fmaf(vr.y, c1i, a1i); a1i = fmaf( vi.y, c1r, a1i);
            // step both chains by stepy^2
            float t;
            t   = fmaf(c0r, sy2_re, -c0i * sy2_im);
            c0i = fmaf(c0r, sy2_im,  c0i * sy2_re); c0r = t;
            t   = fmaf(c1r, sy2_re, -c1i * sy2_im);
            c1i = fmaf(c1r, sy2_im,  c1i * sy2_re); c1r = t;
            // elements 4*yq+2 (chain0), 4*yq+3 (chain1)
            a0r = fmaf(vr.z, c0r, a0r); a0r = fmaf(-vi.z, c0i, a0r);
            a0i = fmaf(vr.z, c0i, a0i); a0i = fmaf( vi.z, c0r, a0i);
            a1r = fmaf(vr.w, c1r, a1r); a1r = fmaf(-vi.w, c1i, a1r);
            a1i = fmaf(vr.w, c1i, a1i); a1i = fmaf( vi.w, c1r, a1i);
            t   = fmaf(c0r, sy2_re, -c0i * sy2_im);
            c0i = fmaf(c0r, sy2_im,  c0i * sy2_re); c0r = t;
            t   = fmaf(c1r, sy2_re, -c1i * sy2_im);
            c1i = fmaf(c1r, sy2_im,  c1i * sy2_re); c1r = t;
        }
        // rowp *= stepx
        const float nrr = fmaf(rowp_re, stepx_re, -rowp_im * stepx_im);
        rowp_im         = fmaf(rowp_re, stepx_im,  rowp_im * stepx_re);
        rowp_re = nrr;
        pre += Wn / 4; pim += Wn / 4;
    }

    const float acc_re = a0r + a1r;
    const float acc_im = a0i + a1i;

    // cross-wave reduction (8 partial sums per k)
    __shared__ float red_re[WAVES][KPB];
    __shared__ float red_im[WAVES][KPB];
    red_re[wave][lane] = acc_re;
    red_im[wave][lane] = acc_im;
    __syncthreads();

    if (threadIdx.x < KPB) {
        float r = 0.f, i2 = 0.f;
        #pragma unroll
        for (int w = 0; w < WAVES; ++w) {
            r  += red_re[w][threadIdx.x];
            i2 += red_im[w][threadIdx.x];
        }
        const int kk = kc * KPB + (int)threadIdx.x;
        if (OUT_COMPLEX) {
            out[((size_t)bc * Kn + kk) * 2 + 0] = r;
            out[((size_t)bc * Kn + kk) * 2 + 1] = i2;
        } else {
            out[(size_t)bc * Kn + kk] = r;   // harness kept only the real part
        }
    }
}

extern "C" void kernel_launch(void* const* d_in, const int* in_sizes, int n_in,
                              void* d_out, int out_size, void* d_ws, size_t ws_size,
                              hipStream_t stream) {
    const float* img_re = (const float*)d_in[0];
    const float* img_im = (const float*)d_in[1];
    const float* traj   = (const float*)d_in[2];
    float* out = (float*)d_out;

    dim3 grid(Bn * Cn * (Kn / KPB));  // 512 blocks -> 2 per CU
    dim3 block(WAVES * 64);           // 512 threads = 8 waves

    if (out_size == Bn * Cn * Kn * 2) {
        hipLaunchKernelGGL((nufft_kernel<1>), grid, block, 0, stream, img_re, img_im, traj, out);
    } else {
        hipLaunchKernelGGL((nufft_kernel<0>), grid, block, 0, stream, img_re, img_im, traj, out);
    }
}

// Round 3
// 27.843 us; speedup vs baseline: 5.1089x; 5.1089x over previous
//
#include <hip/hip_runtime.h>
#include <math.h>

// NUFFT type-2 exact NUDFT via MFMA:
//   tmp[k,x] = sum_y py[k,y] * img[x,y]      (complex GEMM, f16 MFMA, fp32 acc)
//   out[k]   = sum_x tmp[k,x] * px[k,x]      (VALU epilogue on accumulators)
// py/px phases built in-register by complex geometric recurrence (no LDS, no phase tables).

using half8  = __attribute__((ext_vector_type(8))) _Float16;
using half4  = __attribute__((ext_vector_type(4))) _Float16;
using f32x4  = __attribute__((ext_vector_type(4))) float;

constexpr int Bn = 2, Cn = 8, Kn = 2048, Hn = 128, Wn = 128;
constexpr int BC  = Bn * Cn;       // 16
constexpr int KPW = 16;            // k's per wave (one MFMA M-tile)
constexpr int WPB = 4;             // waves per block
constexpr int KPB = KPW * WPB;     // 64 k's per block
constexpr int NXT = Wn / 16;       // 8 x-tiles (N dim)
constexpr int NKS = Hn / 32;       // 4 K-steps over y

// ---- prep: fp32 image -> f16 in workspace ----
__global__ __launch_bounds__(256)
void cvt_f16(const float* __restrict__ re, const float* __restrict__ im,
             _Float16* __restrict__ re16, _Float16* __restrict__ im16)
{
    const int n4 = BC * Hn * Wn / 4;          // 65536 float4-groups per array
    int t = blockIdx.x * 256 + threadIdx.x;   // 0 .. 2*n4-1
    const float* src = (t < n4) ? re : im;
    _Float16*    dst = (t < n4) ? re16 : im16;
    int i = (t < n4) ? t : (t - n4);
    float4 v = ((const float4*)src)[i];
    half4 h;
    h[0] = (_Float16)v.x; h[1] = (_Float16)v.y;
    h[2] = (_Float16)v.z; h[3] = (_Float16)v.w;
    ((half4*)dst)[i] = h;
}

__device__ inline void cmul(float& ar, float& ai, float br, float bi) {
    float nr = fmaf(ar, br, -ai * bi);
    ai = fmaf(ar, bi, ai * br);
    ar = nr;
}

template<int OUT_COMPLEX, int ONFLY>
__global__ __launch_bounds__(256, 2)
void nufft_mfma(const float* __restrict__ img_re, const float* __restrict__ img_im,
                const _Float16* __restrict__ re16, const _Float16* __restrict__ im16,
                const float* __restrict__ traj, float* __restrict__ out)
{
    const int bc   = blockIdx.x / (Kn / KPB);   // 0..15
    const int kt   = blockIdx.x % (Kn / KPB);   // 0..31
    const int wave = threadIdx.x >> 6;
    const int lane = threadIdx.x & 63;
    const int xlo  = lane & 15;                 // n-lane / A-row lane
    const int grp  = lane >> 4;                 // k-slot group
    const int kbase = kt * KPB + wave * KPW;

    // ---- A (py) phase state: lane's A-row k = kbase + xlo ----
    const float om_y = traj[(size_t)(bc * 2 + 1) * Kn + (kbase + xlo)];
    float s, c;
    sincosf(om_y, &s, &c);
    float syr = c, syi = -s;                          // exp(-i*om_y)
    sincosf(om_y * (float)(grp * 8 - 64), &s, &c);
    float pr = c, pi = -s;                            // phase at y = grp*8 (gy = grp*8-64)
    float t32r = syr, t32i = syi;                     // s_y^32
    #pragma unroll
    for (int q = 0; q < 5; ++q) {
        float nr = fmaf(t32r, t32r, -t32i * t32i);
        t32i = 2.f * t32r * t32i;
        t32r = nr;
    }

    f32x4 accr[NXT], acci[NXT];
    #pragma unroll
    for (int xt = 0; xt < NXT; ++xt) { accr[xt] = (f32x4)0.f; acci[xt] = (f32x4)0.f; }

    const size_t ibase = (size_t)bc * Hn * Wn;

    for (int kk = 0; kk < NKS; ++kk) {
        // build py fragment: 8 consecutive y phases starting at y = kk*32 + grp*8
        float vr[8], vi[8];
        vr[0] = pr; vi[0] = pi;
        #pragma unroll
        for (int j = 1; j < 8; ++j) {
            float nr = fmaf(vr[j-1], syr, -vi[j-1] * syi);
            vi[j]    = fmaf(vr[j-1], syi,  vi[j-1] * syr);
            vr[j]    = nr;
        }
        half8 ar, ai8, ani;
        #pragma unroll
        for (int j = 0; j < 8; ++j) {
            ar[j]  = (_Float16)vr[j];
            ai8[j] = (_Float16)vi[j];
            ani[j] = (_Float16)(-vi[j]);
        }
        cmul(pr, pi, t32r, t32i);                     // advance to next K-step

        const int y0 = kk * 32 + grp * 8;
        #pragma unroll
        for (int xt = 0; xt < NXT; ++xt) {
            const int x = xt * 16 + xlo;
            half8 br, bi;
            if (ONFLY) {
                const float* p0 = img_re + ibase + (size_t)x * Wn + y0;
                const float* p1 = img_im + ibase + (size_t)x * Wn + y0;
                float4 a = ((const float4*)p0)[0], b = ((const float4*)p0)[1];
                float4 d = ((const float4*)p1)[0], e = ((const float4*)p1)[1];
                br[0]=(_Float16)a.x; br[1]=(_Float16)a.y; br[2]=(_Float16)a.z; br[3]=(_Float16)a.w;
                br[4]=(_Float16)b.x; br[5]=(_Float16)b.y; br[6]=(_Float16)b.z; br[7]=(_Float16)b.w;
                bi[0]=(_Float16)d.x; bi[1]=(_Float16)d.y; bi[2]=(_Float16)d.z; bi[3]=(_Float16)d.w;
                bi[4]=(_Float16)e.x; bi[5]=(_Float16)e.y; bi[6]=(_Float16)e.z; bi[7]=(_Float16)e.w;
            } else {
                br = *(const half8*)(re16 + ibase + (size_t)x * Wn + y0);
                bi = *(const half8*)(im16 + ibase + (size_t)x * Wn + y0);
            }
            // tmp_re += pyr*ir - pyi*ii ; tmp_im += pyr*ii + pyi*ir
            accr[xt] = __builtin_amdgcn_mfma_f32_16x16x32_f16(ar,  br, accr[xt], 0, 0, 0);
            accr[xt] = __builtin_amdgcn_mfma_f32_16x16x32_f16(ani, bi, accr[xt], 0, 0, 0);
            acci[xt] = __builtin_amdgcn_mfma_f32_16x16x32_f16(ar,  bi, acci[xt], 0, 0, 0);
            acci[xt] = __builtin_amdgcn_mfma_f32_16x16x32_f16(ai8, br, acci[xt], 0, 0, 0);
        }
    }

    // ---- epilogue: out[k] = sum_x tmp[k,x] * px[k,x] ----
    // lane holds tmp[kbase + grp*4 + r, x = xt*16 + xlo] in acc*[xt][r]
    float outr[4], outi[4];
    #pragma unroll
    for (int r = 0; r < 4; ++r) {
        const int kr = kbase + grp * 4 + r;
        const float om_x = traj[(size_t)(bc * 2 + 0) * Kn + kr];
        sincosf(om_x, &s, &c);
        float sxr = c, sxi = -s;                      // exp(-i*om_x)
        sincosf(om_x * (float)(xlo - 64), &s, &c);
        float qr = c, qi = -s;                        // phase at x = xlo
        float t16r = sxr, t16i = sxi;                 // s_x^16
        #pragma unroll
        for (int q = 0; q < 4; ++q) {
            float nr = fmaf(t16r, t16r, -t16i * t16i);
            t16i = 2.f * t16r * t16i;
            t16r = nr;
        }
        float orr = 0.f, oii = 0.f;
        #pragma unroll
        for (int xt = 0; xt < NXT; ++xt) {
            const float tre = accr[xt][r], tim = acci[xt][r];
            orr = fmaf(tre, qr, orr); orr = fmaf(-tim, qi, orr);
            oii = fmaf(tre, qi, oii); oii = fmaf( tim, qr, oii);
            cmul(qr, qi, t16r, t16i);
        }
        // butterfly reduce over the 16-lane x group
        #pragma unroll
        for (int m = 1; m < 16; m <<= 1) {
            orr += __shfl_xor(orr, m, 64);
            oii += __shfl_xor(oii, m, 64);
        }
        outr[r] = orr; outi[r] = oii;
    }

    if (xlo == 0) {
        #pragma unroll
        for (int r = 0; r < 4; ++r) {
            const int kr = kbase + grp * 4 + r;
            if (OUT_COMPLEX) {
                out[((size_t)bc * Kn + kr) * 2 + 0] = outr[r];
                out[((size_t)bc * Kn + kr) * 2 + 1] = outi[r];
            } else {
                out[(size_t)bc * Kn + kr] = outr[r];
            }
        }
    }
}

extern "C" void kernel_launch(void* const* d_in, const int* in_sizes, int n_in,
                              void* d_out, int out_size, void* d_ws, size_t ws_size,
                              hipStream_t stream) {
    const float* img_re = (const float*)d_in[0];
    const float* img_im = (const float*)d_in[1];
    const float* traj   = (const float*)d_in[2];
    float* out = (float*)d_out;

    const size_t nimg = (size_t)BC * Hn * Wn;           // 262144 per array
    const bool useWs = ws_size >= 2 * nimg * sizeof(_Float16);   // 1 MiB
    _Float16* re16 = (_Float16*)d_ws;
    _Float16* im16 = re16 + nimg;

    if (useWs) {
        const int total = (int)(2 * nimg / 4);          // 131072 threads
        hipLaunchKernelGGL(cvt_f16, dim3((total + 255) / 256), dim3(256), 0, stream,
                           img_re, img_im, re16, im16);
    }

    dim3 grid(BC * (Kn / KPB));   // 512 blocks
    dim3 block(WPB * 64);         // 256 threads
    const bool cplx = (out_size == BC * Kn * 2);

    if (useWs) {
        if (cplx) hipLaunchKernelGGL((nufft_mfma<1,0>), grid, block, 0, stream, img_re, img_im, re16, im16, traj, out);
        else      hipLaunchKernelGGL((nufft_mfma<0,0>), grid, block, 0, stream, img_re, img_im, re16, im16, traj, out);
    } else {
        if (cplx) hipLaunchKernelGGL((nufft_mfma<1,1>), grid, block, 0, stream, img_re, img_im, re16, im16, traj, out);
        else      hipLaunchKernelGGL((nufft_mfma<0,1>), grid, block, 0, stream, img_re, img_im, re16, im16, traj, out);
    }
}

// Round 4
// 18.411 us; speedup vs baseline: 7.7264x; 1.5123x over previous
//
#include <hip/hip_runtime.h>
#include <math.h>

// NUFFT type-2 exact NUDFT via MFMA, LDS-resident B:
//   stage f16 image (64KB re+im) into LDS once per block (global_load_lds, XOR-swizzled)
//   tmp[k,x] = sum_y py[k,y] * img[x,y]   (f16 MFMA from LDS, fp32 acc)
//   out[k]   = sum_x tmp[k,x] * px[k,x]   (VALU epilogue on accumulators)
// Phases built in-register by complex geometric recurrence.

using half8  = __attribute__((ext_vector_type(8))) _Float16;
using half4  = __attribute__((ext_vector_type(4))) _Float16;
using f32x4  = __attribute__((ext_vector_type(4))) float;

constexpr int Bn = 2, Cn = 8, Kn = 2048, Hn = 128, Wn = 128;
constexpr int BC  = Bn * Cn;       // 16
constexpr int KPW = 16;            // k's per wave (one MFMA M-tile)
constexpr int WPB = 4;             // waves per block
constexpr int KPB = KPW * WPB;     // 64 k's per block
constexpr int NXT = Wn / 16;       // 8 x-tiles (N dim)
constexpr int NKS = Hn / 32;       // 4 K-steps over y
constexpr int SLOTS = Hn * Wn / 8; // 2048 half8 slots per component (32KB)

// ---- prep: fp32 image -> f16 in workspace ----
__global__ __launch_bounds__(256)
void cvt_f16(const float* __restrict__ re, const float* __restrict__ im,
             _Float16* __restrict__ re16, _Float16* __restrict__ im16)
{
    const int n4 = BC * Hn * Wn / 4;          // 65536 float4-groups per array
    int t = blockIdx.x * 256 + threadIdx.x;   // 0 .. 2*n4-1
    const float* src = (t < n4) ? re : im;
    _Float16*    dst = (t < n4) ? re16 : im16;
    int i = (t < n4) ? t : (t - n4);
    float4 v = ((const float4*)src)[i];
    half4 h;
    h[0] = (_Float16)v.x; h[1] = (_Float16)v.y;
    h[2] = (_Float16)v.z; h[3] = (_Float16)v.w;
    ((half4*)dst)[i] = h;
}

__device__ inline void cmul(float& ar, float& ai, float br, float bi) {
    float nr = fmaf(ar, br, -ai * bi);
    ai = fmaf(ar, bi, ai * br);
    ar = nr;
}

__device__ inline void gload_lds16(const void* g, void* l) {
    auto gp = (const __attribute__((address_space(1))) unsigned int*)g;
    auto lp = (__attribute__((address_space(3))) unsigned int*)(unsigned int)(unsigned long long)l;
    __builtin_amdgcn_global_load_lds(gp, lp, 16, 0, 0);
}

template<int OUT_COMPLEX, int ONFLY>
__global__ __launch_bounds__(256, 2)
void nufft_mfma(const float* __restrict__ img_re, const float* __restrict__ img_im,
                const _Float16* __restrict__ re16, const _Float16* __restrict__ im16,
                const float* __restrict__ traj, float* __restrict__ out)
{
    __shared__ half8 re_lds[SLOTS];   // 32KB
    __shared__ half8 im_lds[SLOTS];   // 32KB

    const int bc   = blockIdx.x / (Kn / KPB);   // 0..15
    const int kt   = blockIdx.x % (Kn / KPB);   // 0..31
    const int wave = threadIdx.x >> 6;
    const int lane = threadIdx.x & 63;
    const int xlo  = lane & 15;                 // n-lane (x within tile) / A k-row lane
    const int grp  = lane >> 4;                 // k-slot group (y-offset group)
    const int kbase = kt * KPB + wave * KPW;
    const size_t ibase = (size_t)bc * Hn * Wn;

    // ---- stage f16 image into LDS, XOR-swizzled: slot s holds (x = s>>4, j = (s&15)^(x&7)) ----
    if (ONFLY) {
        // fallback: load fp32, convert, ds_write (same swizzled layout)
        #pragma unroll
        for (int i = 0; i < 8; ++i) {
            const int s = i * 256 + (int)threadIdx.x;
            const int x = s >> 4;
            const int j = (s & 15) ^ (x & 7);
            const float* gr = img_re + ibase + (size_t)x * Wn + j * 8;
            const float* gi = img_im + ibase + (size_t)x * Wn + j * 8;
            float4 a = ((const float4*)gr)[0], b = ((const float4*)gr)[1];
            float4 d = ((const float4*)gi)[0], e = ((const float4*)gi)[1];
            half8 hr, hi;
            hr[0]=(_Float16)a.x; hr[1]=(_Float16)a.y; hr[2]=(_Float16)a.z; hr[3]=(_Float16)a.w;
            hr[4]=(_Float16)b.x; hr[5]=(_Float16)b.y; hr[6]=(_Float16)b.z; hr[7]=(_Float16)b.w;
            hi[0]=(_Float16)d.x; hi[1]=(_Float16)d.y; hi[2]=(_Float16)d.z; hi[3]=(_Float16)d.w;
            hi[4]=(_Float16)e.x; hi[5]=(_Float16)e.y; hi[6]=(_Float16)e.z; hi[7]=(_Float16)e.w;
            re_lds[s] = hr;
            im_lds[s] = hi;
        }
    } else {
        // async direct-to-LDS: dest linear (wave-uniform base + lane*16), source pre-inverse-swizzled
        #pragma unroll
        for (int i = 0; i < 8; ++i) {
            const int s = wave * 512 + i * 64 + lane;
            const int x = s >> 4;
            const int j = (s & 15) ^ (x & 7);
            gload_lds16(re16 + ibase + (size_t)x * Wn + j * 8, &re_lds[wave * 512 + i * 64]);
            gload_lds16(im16 + ibase + (size_t)x * Wn + j * 8, &im_lds[wave * 512 + i * 64]);
        }
    }

    // ---- A (py) phase state while staging lands: lane's A-row k = kbase + xlo ----
    const float om_y = traj[(size_t)(bc * 2 + 1) * Kn + (kbase + xlo)];
    float s, c;
    sincosf(om_y, &s, &c);
    float syr = c, syi = -s;                          // exp(-i*om_y)
    sincosf(om_y * (float)(grp * 8 - 64), &s, &c);
    float pr = c, pi = -s;                            // phase at y = grp*8
    float t32r = syr, t32i = syi;                     // s_y^32
    #pragma unroll
    for (int q = 0; q < 5; ++q) {
        float nr = fmaf(t32r, t32r, -t32i * t32i);
        t32i = 2.f * t32r * t32i;
        t32r = nr;
    }

    f32x4 accr[NXT], acci[NXT];
    #pragma unroll
    for (int xt = 0; xt < NXT; ++xt) { accr[xt] = (f32x4)0.f; acci[xt] = (f32x4)0.f; }

    __syncthreads();   // staging complete (compiler drains vmcnt before barrier)

    for (int kk = 0; kk < NKS; ++kk) {
        // build py fragment: 8 consecutive y phases starting at y = kk*32 + grp*8
        float vr[8], vi[8];
        vr[0] = pr; vi[0] = pi;
        #pragma unroll
        for (int j = 1; j < 8; ++j) {
            float nr = fmaf(vr[j-1], syr, -vi[j-1] * syi);
            vi[j]    = fmaf(vr[j-1], syi,  vi[j-1] * syr);
            vr[j]    = nr;
        }
        half8 ar, ai8, ani;
        #pragma unroll
        for (int j = 0; j < 8; ++j) {
            ar[j]  = (_Float16)vr[j];
            ai8[j] = (_Float16)vi[j];
            ani[j] = (_Float16)(-vi[j]);
        }
        cmul(pr, pi, t32r, t32i);                     // advance to next K-step

        const int jx = (kk * 4 + grp) ^ (xlo & 7);    // swizzled y-slot for this lane
        #pragma unroll
        for (int xt = 0; xt < NXT; ++xt) {
            const int slot = (xt * 16 + xlo) * 16 + jx;
            half8 br = re_lds[slot];
            half8 bi = im_lds[slot];
            accr[xt] = __builtin_amdgcn_mfma_f32_16x16x32_f16(ar,  br, accr[xt], 0, 0, 0);
            accr[xt] = __builtin_amdgcn_mfma_f32_16x16x32_f16(ani, bi, accr[xt], 0, 0, 0);
            acci[xt] = __builtin_amdgcn_mfma_f32_16x16x32_f16(ar,  bi, acci[xt], 0, 0, 0);
            acci[xt] = __builtin_amdgcn_mfma_f32_16x16x32_f16(ai8, br, acci[xt], 0, 0, 0);
        }
    }

    // ---- epilogue: out[k] = sum_x tmp[k,x] * px[k,x] ----
    // lane holds tmp[kbase + grp*4 + r, x = xt*16 + xlo] in acc*[xt][r]
    float outr[4], outi[4];
    #pragma unroll
    for (int r = 0; r < 4; ++r) {
        const int kr = kbase + grp * 4 + r;
        const float om_x = traj[(size_t)(bc * 2 + 0) * Kn + kr];
        sincosf(om_x, &s, &c);
        float sxr = c, sxi = -s;                      // exp(-i*om_x)
        sincosf(om_x * (float)(xlo - 64), &s, &c);
        float qr = c, qi = -s;                        // phase at x = xlo
        float t16r = sxr, t16i = sxi;                 // s_x^16
        #pragma unroll
        for (int q = 0; q < 4; ++q) {
            float nr = fmaf(t16r, t16r, -t16i * t16i);
            t16i = 2.f * t16r * t16i;
            t16r = nr;
        }
        float orr = 0.f, oii = 0.f;
        #pragma unroll
        for (int xt = 0; xt < NXT; ++xt) {
            const float tre = accr[xt][r], tim = acci[xt][r];
            orr = fmaf(tre, qr, orr); orr = fmaf(-tim, qi, orr);
            oii = fmaf(tre, qi, oii); oii = fmaf( tim, qr, oii);
            cmul(qr, qi, t16r, t16i);
        }
        #pragma unroll
        for (int m = 1; m < 16; m <<= 1) {
            orr += __shfl_xor(orr, m, 64);
            oii += __shfl_xor(oii, m, 64);
        }
        outr[r] = orr; outi[r] = oii;
    }

    if (xlo == 0) {
        #pragma unroll
        for (int r = 0; r < 4; ++r) {
            const int kr = kbase + grp * 4 + r;
            if (OUT_COMPLEX) {
                out[((size_t)bc * Kn + kr) * 2 + 0] = outr[r];
                out[((size_t)bc * Kn + kr) * 2 + 1] = outi[r];
            } else {
                out[(size_t)bc * Kn + kr] = outr[r];
            }
        }
    }
}

extern "C" void kernel_launch(void* const* d_in, const int* in_sizes, int n_in,
                              void* d_out, int out_size, void* d_ws, size_t ws_size,
                              hipStream_t stream) {
    const float* img_re = (const float*)d_in[0];
    const float* img_im = (const float*)d_in[1];
    const float* traj   = (const float*)d_in[2];
    float* out = (float*)d_out;

    const size_t nimg = (size_t)BC * Hn * Wn;           // 262144 per array
    const bool useWs = ws_size >= 2 * nimg * sizeof(_Float16);   // 1 MiB
    _Float16* re16 = (_Float16*)d_ws;
    _Float16* im16 = re16 + nimg;

    if (useWs) {
        const int total = (int)(2 * nimg / 4);          // 131072 threads
        hipLaunchKernelGGL(cvt_f16, dim3((total + 255) / 256), dim3(256), 0, stream,
                           img_re, img_im, re16, im16);
    }

    dim3 grid(BC * (Kn / KPB));   // 512 blocks
    dim3 block(WPB * 64);         // 256 threads
    const bool cplx = (out_size == BC * Kn * 2);

    if (useWs) {
        if (cplx) hipLaunchKernelGGL((nufft_mfma<1,0>), grid, block, 0, stream, img_re, img_im, re16, im16, traj, out);
        else      hipLaunchKernelGGL((nufft_mfma<0,0>), grid, block, 0, stream, img_re, img_im, re16, im16, traj, out);
    } else {
        if (cplx) hipLaunchKernelGGL((nufft_mfma<1,1>), grid, block, 0, stream, img_re, img_im, re16, im16, traj, out);
        else      hipLaunchKernelGGL((nufft_mfma<0,1>), grid, block, 0, stream, img_re, img_im, re16, im16, traj, out);
    }
}

// Round 7
// 17.822 us; speedup vs baseline: 7.9817x; 1.0330x over previous
//
#include <hip/hip_runtime.h>
#include <math.h>

// NUFFT type-2 exact NUDFT via MFMA, LDS-resident B.
// R7: R4's VERIFIED 4-wave dataflow, with two-phase 32KB LDS staging (64 image rows
// per phase) to double occupancy (2 -> 4 blocks/CU, 4 waves/SIMD).
//   tmp[k,x] = sum_y py[k,y]*img[x,y]  (f16 MFMA, fp32 acc)
//   out[k]   = sum_x tmp[k,x]*px[k,x]  (VALU epilogue, 16-lane butterfly, direct store)

using half8  = __attribute__((ext_vector_type(8))) _Float16;
using half4  = __attribute__((ext_vector_type(4))) _Float16;
using f32x4  = __attribute__((ext_vector_type(4))) float;

constexpr int Bn = 2, Cn = 8, Kn = 2048, Hn = 128, Wn = 128;
constexpr int BC  = Bn * Cn;       // 16
constexpr int KPW = 16;            // k's per wave (one MFMA M-tile)
constexpr int WPB = 4;             // waves per block
constexpr int KPB = KPW * WPB;     // 64 k's per block
constexpr int NKS = Hn / 32;       // 4 K-steps over y
constexpr int PSLOTS = 64 * Wn / 8; // 1024 half8 slots per component per phase (16KB)

__device__ inline void cmul(float& ar, float& ai, float br, float bi) {
    float nr = fmaf(ar, br, -ai * bi);
    ai = fmaf(ar, bi, ai * br);
    ar = nr;
}
__device__ inline void csq(float& r, float& i) {
    float nr = fmaf(r, r, -i * i);
    i = 2.f * r * i;
    r = nr;
}

// ---- prep: fp32 image -> f16 in workspace (verified R4 version) ----
__global__ __launch_bounds__(256)
void cvt_f16(const float* __restrict__ re, const float* __restrict__ im,
             _Float16* __restrict__ re16, _Float16* __restrict__ im16)
{
    const int n4 = BC * Hn * Wn / 4;          // 65536 float4-groups per array
    int t = blockIdx.x * 256 + threadIdx.x;   // 0 .. 2*n4-1
    const float* src = (t < n4) ? re : im;
    _Float16*    dst = (t < n4) ? re16 : im16;
    int i = (t < n4) ? t : (t - n4);
    float4 v = ((const float4*)src)[i];
    half4 h;
    h[0] = (_Float16)v.x; h[1] = (_Float16)v.y;
    h[2] = (_Float16)v.z; h[3] = (_Float16)v.w;
    ((half4*)dst)[i] = h;
}

__device__ inline void gload_lds16(const void* g, void* l) {
    auto gp = (const __attribute__((address_space(1))) unsigned int*)g;
    auto lp = (__attribute__((address_space(3))) unsigned int*)(unsigned int)(unsigned long long)l;
    __builtin_amdgcn_global_load_lds(gp, lp, 16, 0, 0);
}

template<int OUT_COMPLEX, int ONFLY>
__global__ __launch_bounds__(256, 4)
void nufft_mfma(const float* __restrict__ img_re, const float* __restrict__ img_im,
                const _Float16* __restrict__ re16, const _Float16* __restrict__ im16,
                const float* __restrict__ traj, float* __restrict__ out)
{
    __shared__ half8 re_lds[PSLOTS];   // 16KB (one 64-row phase)
    __shared__ half8 im_lds[PSLOTS];   // 16KB

    const int bc   = blockIdx.x / (Kn / KPB);   // 0..15
    const int kt   = blockIdx.x % (Kn / KPB);   // 0..31
    const int wave = threadIdx.x >> 6;          // 0..3
    const int lane = threadIdx.x & 63;
    const int xlo  = lane & 15;                 // n-lane (x within tile) / A k-row lane
    const int grp  = lane >> 4;                 // k-slot group (y-offset group)
    const int kbase = kt * KPB + wave * KPW;
    const size_t ibase = (size_t)bc * Hn * Wn;

    // ---- stage phase p (rows [p*64, p*64+64)), XOR-swizzled:
    //      slot s holds (x_local = s>>4, y-chunk j = (s&15)^(x_local&7)) ----
    auto STAGE = [&](int p) {
        if (ONFLY) {
            #pragma unroll
            for (int i = 0; i < 4; ++i) {
                const int s = i * 256 + (int)threadIdx.x;   // 0..1023
                const int xl = s >> 4;
                const int j = (s & 15) ^ (xl & 7);
                const float* gr = img_re + ibase + (size_t)(p * 64 + xl) * Wn + j * 8;
                const float* gi = img_im + ibase + (size_t)(p * 64 + xl) * Wn + j * 8;
                float4 a = ((const float4*)gr)[0], b = ((const float4*)gr)[1];
                float4 d = ((const float4*)gi)[0], e = ((const float4*)gi)[1];
                half8 hr, hi;
                hr[0]=(_Float16)a.x; hr[1]=(_Float16)a.y; hr[2]=(_Float16)a.z; hr[3]=(_Float16)a.w;
                hr[4]=(_Float16)b.x; hr[5]=(_Float16)b.y; hr[6]=(_Float16)b.z; hr[7]=(_Float16)b.w;
                hi[0]=(_Float16)d.x; hi[1]=(_Float16)d.y; hi[2]=(_Float16)d.z; hi[3]=(_Float16)d.w;
                hi[4]=(_Float16)e.x; hi[5]=(_Float16)e.y; hi[6]=(_Float16)e.z; hi[7]=(_Float16)e.w;
                re_lds[s] = hr;
                im_lds[s] = hi;
            }
        } else {
            #pragma unroll
            for (int i = 0; i < 4; ++i) {
                const int s = wave * 256 + i * 64 + lane;   // 0..1023
                const int xl = s >> 4;
                const int j = (s & 15) ^ (xl & 7);
                gload_lds16(re16 + ibase + (size_t)(p * 64 + xl) * Wn + j * 8,
                            &re_lds[wave * 256 + i * 64]);
                gload_lds16(im16 + ibase + (size_t)(p * 64 + xl) * Wn + j * 8,
                            &im_lds[wave * 256 + i * 64]);
            }
        }
    };

    STAGE(0);

    // ---- A (py) phase state (R4-verified): lane's A-row k = kbase + xlo ----
    const float om_y = traj[(size_t)(bc * 2 + 1) * Kn + (kbase + xlo)];
    float s, c;
    sincosf(om_y, &s, &c);
    const float syr = c, syi = -s;                    // exp(-i*om_y)
    sincosf(om_y * (float)(grp * 8 - 64), &s, &c);
    const float pr0 = c, pi0 = -s;                    // phase at y = grp*8
    float t32r = syr, t32i = syi;                     // s_y^32
    #pragma unroll
    for (int q = 0; q < 5; ++q) csq(t32r, t32i);

    f32x4 accr[8], acci[8];
    #pragma unroll
    for (int a = 0; a < 8; ++a) { accr[a] = (f32x4)0.f; acci[a] = (f32x4)0.f; }

    __syncthreads();   // phase-0 staging complete

    #pragma unroll
    for (int p = 0; p < 2; ++p) {
        float pr = pr0, pi = pi0;
        for (int kk = 0; kk < NKS; ++kk) {
            float vr[8], vi[8];
            vr[0] = pr; vi[0] = pi;
            #pragma unroll
            for (int j = 1; j < 8; ++j) {
                float nr = fmaf(vr[j-1], syr, -vi[j-1] * syi);
                vi[j]    = fmaf(vr[j-1], syi,  vi[j-1] * syr);
                vr[j]    = nr;
            }
            half8 ar, ai8, ani;
            #pragma unroll
            for (int j = 0; j < 8; ++j) {
                ar[j]  = (_Float16)vr[j];
                ai8[j] = (_Float16)vi[j];
                ani[j] = (_Float16)(-vi[j]);
            }
            cmul(pr, pi, t32r, t32i);

            const int jx = (kk * 4 + grp) ^ (xlo & 7);
            #pragma unroll
            for (int xt = 0; xt < 4; ++xt) {
                const int slot = (xt * 16 + xlo) * 16 + jx;
                half8 br = re_lds[slot];
                half8 bi = im_lds[slot];
                const int a = p * 4 + xt;   // global x = a*16 + xlo
                accr[a] = __builtin_amdgcn_mfma_f32_16x16x32_f16(ar,  br, accr[a], 0, 0, 0);
                accr[a] = __builtin_amdgcn_mfma_f32_16x16x32_f16(ani, bi, accr[a], 0, 0, 0);
                acci[a] = __builtin_amdgcn_mfma_f32_16x16x32_f16(ar,  bi, acci[a], 0, 0, 0);
                acci[a] = __builtin_amdgcn_mfma_f32_16x16x32_f16(ai8, br, acci[a], 0, 0, 0);
            }
        }
        if (p == 0) {
            __syncthreads();   // everyone done reading phase-0 LDS
            STAGE(1);
            __syncthreads();   // phase-1 staging complete
        }
    }

    // ---- epilogue (R4-verified, unchanged): out[k] = sum_x tmp[k,x]*px[k,x] ----
    // lane holds tmp[kbase + grp*4 + r, x = a*16 + xlo] in acc*[a][r]
    float outr[4], outi[4];
    #pragma unroll
    for (int r = 0; r < 4; ++r) {
        const int kr = kbase + grp * 4 + r;
        const float om_x = traj[(size_t)(bc * 2 + 0) * Kn + kr];
        sincosf(om_x, &s, &c);
        float t16r = c, t16i = -s;                    // exp(-i*om_x)
        sincosf(om_x * (float)(xlo - 64), &s, &c);
        float qr = c, qi = -s;                        // phase at x = xlo
        #pragma unroll
        for (int q = 0; q < 4; ++q) csq(t16r, t16i);  // s_x^16
        float orr = 0.f, oii = 0.f;
        #pragma unroll
        for (int a = 0; a < 8; ++a) {
            const float tre = accr[a][r], tim = acci[a][r];
            orr = fmaf(tre, qr, orr); orr = fmaf(-tim, qi, orr);
            oii = fmaf(tre, qi, oii); oii = fmaf( tim, qr, oii);
            cmul(qr, qi, t16r, t16i);
        }
        #pragma unroll
        for (int m = 1; m < 16; m <<= 1) {
            orr += __shfl_xor(orr, m, 64);
            oii += __shfl_xor(oii, m, 64);
        }
        outr[r] = orr; outi[r] = oii;
    }

    if (xlo == 0) {
        #pragma unroll
        for (int r = 0; r < 4; ++r) {
            const int kr = kbase + grp * 4 + r;
            if (OUT_COMPLEX) {
                out[((size_t)bc * Kn + kr) * 2 + 0] = outr[r];
                out[((size_t)bc * Kn + kr) * 2 + 1] = outi[r];
            } else {
                out[(size_t)bc * Kn + kr] = outr[r];
            }
        }
    }
}

extern "C" void kernel_launch(void* const* d_in, const int* in_sizes, int n_in,
                              void* d_out, int out_size, void* d_ws, size_t ws_size,
                              hipStream_t stream) {
    const float* img_re = (const float*)d_in[0];
    const float* img_im = (const float*)d_in[1];
    const float* traj   = (const float*)d_in[2];
    float* out = (float*)d_out;

    const size_t nimg = (size_t)BC * Hn * Wn;           // 262144 per array
    const bool useWs = ws_size >= 2 * nimg * sizeof(_Float16);   // 1 MiB
    _Float16* re16 = (_Float16*)d_ws;
    _Float16* im16 = re16 + nimg;

    if (useWs) {
        const int total = (int)(2 * nimg / 4);          // 131072 threads
        hipLaunchKernelGGL(cvt_f16, dim3((total + 255) / 256), dim3(256), 0, stream,
                           img_re, img_im, re16, im16);
    }

    dim3 grid(BC * (Kn / KPB));   // 512 blocks
    dim3 block(WPB * 64);         // 256 threads
    const bool cplx = (out_size == BC * Kn * 2);

    if (useWs) {
        if (cplx) hipLaunchKernelGGL((nufft_mfma<1,0>), grid, block, 0, stream, img_re, img_im, re16, im16, traj, out);
        else      hipLaunchKernelGGL((nufft_mfma<0,0>), grid, block, 0, stream, img_re, img_im, re16, im16, traj, out);
    } else {
        if (cplx) hipLaunchKernelGGL((nufft_mfma<1,1>), grid, block, 0, stream, img_re, img_im, re16, im16, traj, out);
        else      hipLaunchKernelGGL((nufft_mfma<0,1>), grid, block, 0, stream, img_re, img_im, re16, im16, traj, out);
    }
}

// Round 10
// 12.793 us; speedup vs baseline: 11.1193x; 1.3931x over previous
//
#include <hip/hip_runtime.h>
#include <math.h>

// NUFFT type-2 exact NUDFT via MFMA, LDS-resident B.
// R10: R7's VERIFIED two-phase dataflow, fused to a SINGLE kernel: the staging
// loop loads fp32 image directly, converts to f16 in-register, and ds_writes the
// XOR-swizzled LDS tile (no workspace, no prep kernel, no gload_lds).
//   tmp[k,x] = sum_y py[k,y]*img[x,y]  (f16 MFMA, fp32 acc)
//   out[k]   = sum_x tmp[k,x]*px[k,x]  (VALU epilogue, 16-lane butterfly, direct store)

using half8  = __attribute__((ext_vector_type(8))) _Float16;
using f32x4  = __attribute__((ext_vector_type(4))) float;

constexpr int Bn = 2, Cn = 8, Kn = 2048, Hn = 128, Wn = 128;
constexpr int BC  = Bn * Cn;        // 16
constexpr int KPW = 16;             // k's per wave (one MFMA M-tile)
constexpr int WPB = 4;              // waves per block
constexpr int KPB = KPW * WPB;      // 64 k's per block
constexpr int NKS = Hn / 32;        // 4 K-steps over y
constexpr int PSLOTS = 64 * Wn / 8; // 1024 half8 slots per component per phase (16KB)

__device__ inline void cmul(float& ar, float& ai, float br, float bi) {
    float nr = fmaf(ar, br, -ai * bi);
    ai = fmaf(ar, bi, ai * br);
    ar = nr;
}
__device__ inline void csq(float& r, float& i) {
    float nr = fmaf(r, r, -i * i);
    i = 2.f * r * i;
    r = nr;
}

template<int OUT_COMPLEX>
__global__ __launch_bounds__(256, 4)
void nufft_mfma(const float* __restrict__ img_re, const float* __restrict__ img_im,
                const float* __restrict__ traj, float* __restrict__ out)
{
    __shared__ half8 re_lds[PSLOTS];   // 16KB (one 64-row phase)
    __shared__ half8 im_lds[PSLOTS];   // 16KB

    const int bc   = blockIdx.x / (Kn / KPB);   // 0..15
    const int kt   = blockIdx.x % (Kn / KPB);   // 0..31
    const int wave = threadIdx.x >> 6;          // 0..3
    const int lane = threadIdx.x & 63;
    const int xlo  = lane & 15;                 // n-lane (x within tile) / A k-row lane
    const int grp  = lane >> 4;                 // k-slot group (y-offset group)
    const int kbase = kt * KPB + wave * KPW;
    const size_t ibase = (size_t)bc * Hn * Wn;

    // ---- stage phase p (rows [p*64, p*64+64)), fp32 -> f16 convert + XOR-swizzle:
    //      slot s holds (x_local = s>>4, y-chunk j = (s&15)^(x_local&7)) ----
    auto STAGE = [&](int p) {
        #pragma unroll
        for (int i = 0; i < 4; ++i) {
            const int s = i * 256 + (int)threadIdx.x;   // 0..1023
            const int xl = s >> 4;
            const int j = (s & 15) ^ (xl & 7);
            const float* gr = img_re + ibase + (size_t)(p * 64 + xl) * Wn + j * 8;
            const float* gi = img_im + ibase + (size_t)(p * 64 + xl) * Wn + j * 8;
            float4 a = ((const float4*)gr)[0], b = ((const float4*)gr)[1];
            float4 d = ((const float4*)gi)[0], e = ((const float4*)gi)[1];
            half8 hr, hi;
            hr[0]=(_Float16)a.x; hr[1]=(_Float16)a.y; hr[2]=(_Float16)a.z; hr[3]=(_Float16)a.w;
            hr[4]=(_Float16)b.x; hr[5]=(_Float16)b.y; hr[6]=(_Float16)b.z; hr[7]=(_Float16)b.w;
            hi[0]=(_Float16)d.x; hi[1]=(_Float16)d.y; hi[2]=(_Float16)d.z; hi[3]=(_Float16)d.w;
            hi[4]=(_Float16)e.x; hi[5]=(_Float16)e.y; hi[6]=(_Float16)e.z; hi[7]=(_Float16)e.w;
            re_lds[s] = hr;
            im_lds[s] = hi;
        }
    };

    STAGE(0);

    // ---- A (py) phase state (verified): lane's A-row k = kbase + xlo ----
    const float om_y = traj[(size_t)(bc * 2 + 1) * Kn + (kbase + xlo)];
    float s, c;
    sincosf(om_y, &s, &c);
    const float syr = c, syi = -s;                    // exp(-i*om_y)
    sincosf(om_y * (float)(grp * 8 - 64), &s, &c);
    const float pr0 = c, pi0 = -s;                    // phase at y = grp*8
    float t32r = syr, t32i = syi;                     // s_y^32
    #pragma unroll
    for (int q = 0; q < 5; ++q) csq(t32r, t32i);

    f32x4 accr[8], acci[8];
    #pragma unroll
    for (int a = 0; a < 8; ++a) { accr[a] = (f32x4)0.f; acci[a] = (f32x4)0.f; }

    __syncthreads();   // phase-0 staging complete

    #pragma unroll
    for (int p = 0; p < 2; ++p) {
        float pr = pr0, pi = pi0;
        for (int kk = 0; kk < NKS; ++kk) {
            float vr[8], vi[8];
            vr[0] = pr; vi[0] = pi;
            #pragma unroll
            for (int j = 1; j < 8; ++j) {
                float nr = fmaf(vr[j-1], syr, -vi[j-1] * syi);
                vi[j]    = fmaf(vr[j-1], syi,  vi[j-1] * syr);
                vr[j]    = nr;
            }
            half8 ar, ai8, ani;
            #pragma unroll
            for (int j = 0; j < 8; ++j) {
                ar[j]  = (_Float16)vr[j];
                ai8[j] = (_Float16)vi[j];
                ani[j] = (_Float16)(-vi[j]);
            }
            cmul(pr, pi, t32r, t32i);

            const int jx = (kk * 4 + grp) ^ (xlo & 7);
            #pragma unroll
            for (int xt = 0; xt < 4; ++xt) {
                const int slot = (xt * 16 + xlo) * 16 + jx;
                half8 br = re_lds[slot];
                half8 bi = im_lds[slot];
                const int a = p * 4 + xt;   // global x = a*16 + xlo
                accr[a] = __builtin_amdgcn_mfma_f32_16x16x32_f16(ar,  br, accr[a], 0, 0, 0);
                accr[a] = __builtin_amdgcn_mfma_f32_16x16x32_f16(ani, bi, accr[a], 0, 0, 0);
                acci[a] = __builtin_amdgcn_mfma_f32_16x16x32_f16(ar,  bi, acci[a], 0, 0, 0);
                acci[a] = __builtin_amdgcn_mfma_f32_16x16x32_f16(ai8, br, acci[a], 0, 0, 0);
            }
        }
        if (p == 0) {
            __syncthreads();   // everyone done reading phase-0 LDS
            STAGE(1);
            __syncthreads();   // phase-1 staging complete
        }
    }

    // ---- epilogue (verified): out[k] = sum_x tmp[k,x]*px[k,x] ----
    // lane holds tmp[kbase + grp*4 + r, x = a*16 + xlo] in acc*[a][r]
    float outr[4], outi[4];
    #pragma unroll
    for (int r = 0; r < 4; ++r) {
        const int kr = kbase + grp * 4 + r;
        const float om_x = traj[(size_t)(bc * 2 + 0) * Kn + kr];
        sincosf(om_x, &s, &c);
        float t16r = c, t16i = -s;                    // exp(-i*om_x)
        sincosf(om_x * (float)(xlo - 64), &s, &c);
        float qr = c, qi = -s;                        // phase at x = xlo
        #pragma unroll
        for (int q = 0; q < 4; ++q) csq(t16r, t16i);  // s_x^16
        float orr = 0.f, oii = 0.f;
        #pragma unroll
        for (int a = 0; a < 8; ++a) {
            const float tre = accr[a][r], tim = acci[a][r];
            orr = fmaf(tre, qr, orr); orr = fmaf(-tim, qi, orr);
            oii = fmaf(tre, qi, oii); oii = fmaf( tim, qr, oii);
            cmul(qr, qi, t16r, t16i);
        }
        #pragma unroll
        for (int m = 1; m < 16; m <<= 1) {
            orr += __shfl_xor(orr, m, 64);
            oii += __shfl_xor(oii, m, 64);
        }
        outr[r] = orr; outi[r] = oii;
    }

    if (xlo == 0) {
        #pragma unroll
        for (int r = 0; r < 4; ++r) {
            const int kr = kbase + grp * 4 + r;
            if (OUT_COMPLEX) {
                out[((size_t)bc * Kn + kr) * 2 + 0] = outr[r];
                out[((size_t)bc * Kn + kr) * 2 + 1] = outi[r];
            } else {
                out[(size_t)bc * Kn + kr] = outr[r];
            }
        }
    }
}

extern "C" void kernel_launch(void* const* d_in, const int* in_sizes, int n_in,
                              void* d_out, int out_size, void* d_ws, size_t ws_size,
                              hipStream_t stream) {
    const float* img_re = (const float*)d_in[0];
    const float* img_im = (const float*)d_in[1];
    const float* traj   = (const float*)d_in[2];
    float* out = (float*)d_out;

    dim3 grid(BC * (Kn / KPB));   // 512 blocks
    dim3 block(WPB * 64);         // 256 threads
    const bool cplx = (out_size == BC * Kn * 2);

    if (cplx) hipLaunchKernelGGL((nufft_mfma<1>), grid, block, 0, stream, img_re, img_im, traj, out);
    else      hipLaunchKernelGGL((nufft_mfma<0>), grid, block, 0, stream, img_re, img_im, traj, out);
}